// Round 15
// baseline (31.384 us; speedup 1.0000x reference)
//
#include <hip/hip_runtime.h>
#include <hip/hip_fp16.h>

#define TWO_PI 6.2831853071795864769f

// ws layout (bytes):
//   Ch    half[393216]    @ 0       (786432)  C = P1 + 0.975*P3 in fp16
//   cnt   int[16]         @ 786432  (64)
//   wde_g int[6][2048]    @ 786496  (49152)   winner (d<<8)|e per b
//   wv_g  f32[3][6][2048] @ 835648  (147456)  per-stage corrections val-P1
//   flags int[16]         @ 983104  (64)      [0]=C-done count, [1]=hash done
//
// ONE dispatch, 169 blocks x 1024 threads (all co-resident: 169 <= 256 CUs,
// <=49KB LDS). Roles: blk 0..95 = C-producers (write fp16 Ch via relaxed
// agent 8B stores -> LLC; __syncthreads drains vmcnt before the done-count
// increment, r10-proven). blk 168 = winner-hash resolver (r6-proven).
// blk 96..167 = 72 chain consumers: load P2/modl first (overlaps producers),
// ONE-SHOT flag wait (not a barrier: no round-trip of computed data), then
// ingest 128KB Ch via L1/L2-BYPASSING relaxed agent loads (stale-line safe),
// then the r11-proven 3-stage chain with fp16 unpack fused into FMAs.
// This removes r14's dispatch gap while keeping its 4x ingest cut
// (per-CU ingest wall ~10 B/cyc is the binding constraint, r3-r14).

__global__ __launch_bounds__(1024, 4) void mega_kernel(
    const float* __restrict__ P1, const float* __restrict__ P2,
    const float* __restrict__ P3, const float* __restrict__ T4,
    const int* __restrict__ p5, const int* __restrict__ p6,
    const int* __restrict__ p7, const int* __restrict__ p8,
    const float* __restrict__ f1, const float* __restrict__ ph1,
    const float* __restrict__ T11, const float* __restrict__ f2,
    const float* __restrict__ ph2, const float* __restrict__ T14,
    const float* __restrict__ f3, const float* __restrict__ ph3,
    __half* __restrict__ Ch, int* __restrict__ cnt,
    int* __restrict__ wde_g, float* __restrict__ wv_g,
    int* __restrict__ flags, float* __restrict__ out, int K)
{
    __shared__ __align__(16) unsigned char smem[49216];
    const int tid = (int)threadIdx.x;
    const int blk = (int)blockIdx.x;

    if (blk < 96) {
        // ---- producer: Ch = fp16(P1 + 0.975*P3), write-through to LLC ----
        int i = blk * 1024 + tid;              // float4 index (96*1024 total)
        float4 a = ((const float4*)P1)[i];
        float4 c = ((const float4*)P3)[i];
        union { __half2 h2[2]; unsigned long long u; } pk_;
        pk_.h2[0] = __floats2half2_rn(fmaf(c.x, 0.975f, a.x),
                                      fmaf(c.y, 0.975f, a.y));
        pk_.h2[1] = __floats2half2_rn(fmaf(c.z, 0.975f, a.z),
                                      fmaf(c.w, 0.975f, a.w));
        __hip_atomic_store((unsigned long long*)Ch + i, pk_.u,
                           __ATOMIC_RELAXED, __HIP_MEMORY_SCOPE_AGENT);
        __syncthreads();                       // vmcnt drained: LLC-visible
        if (tid == 0)
            __hip_atomic_fetch_add(&flags[0], 1, __ATOMIC_RELAXED,
                                   __HIP_MEMORY_SCOPE_AGENT);
        return;
    }

    if (blk == 168) {
        // ---- winner resolver: last-write-wins over (d,e,b), r6-proven ----
        unsigned* pk   = (unsigned*)smem;             // [2048]
        unsigned* hmap = (unsigned*)(smem + 8192);    // [4096]
        int*      scnt = (int*)(smem + 24576);        // [8]
        for (int k = tid; k < K; k += 1024)
            pk[k] = ((unsigned)p5[k] << 24) | ((unsigned)p6[k] << 16) |
                    ((unsigned)p7[k] << 8) | (unsigned)p8[k];
        for (int i = tid; i < 4096; i += 1024) hmap[i] = 0xFFFFFFFFu;
        if (tid < 8) scnt[tid] = 0;
        __syncthreads();
        for (int k = tid; k < K; k += 1024) {
            unsigned v = pk[k];
            unsigned key  = v & 0xFFFFu;                  // (d<<8)|e
            unsigned full = (key << 3) | (v >> 24);       // (d,e,b)
            unsigned mine = (full << 12) | (unsigned)k;
            unsigned hh = (full * 2654435761u) >> 20;
            for (;;) {
                unsigned prev = atomicCAS(&hmap[hh], 0xFFFFFFFFu, mine);
                if (prev == 0xFFFFFFFFu) break;
                if ((prev >> 12) == full) { atomicMax(&hmap[hh], mine); break; }
                hh = (hh + 1) & 4095u;
            }
        }
        __syncthreads();
        for (int k = tid; k < K; k += 1024) {
            unsigned v = pk[k];
            unsigned key  = v & 0xFFFFu;
            unsigned full = (key << 3) | (v >> 24);
            unsigned hh = (full * 2654435761u) >> 20;
            unsigned cur;
            for (;;) {
                cur = hmap[hh];
                if ((cur >> 12) == full) break;
                hh = (hh + 1) & 4095u;
            }
            if ((cur & 0xFFFu) == (unsigned)k) {          // last write wins
                int b = (int)(v >> 24), c = (int)((v >> 16) & 0xFFu);
                float p1v = P1[(b << 16) | key];          // exact fp32
                int w = atomicAdd(&scnt[b], 1);
                __hip_atomic_store(&wde_g[b * 2048 + w], (int)key,
                                   __ATOMIC_RELAXED, __HIP_MEMORY_SCOPE_AGENT);
                __hip_atomic_store(&wv_g[(0 * 6 + b) * 2048 + w],
                                   T4[b * 256 + c] - p1v,
                                   __ATOMIC_RELAXED, __HIP_MEMORY_SCOPE_AGENT);
                __hip_atomic_store(&wv_g[(1 * 6 + b) * 2048 + w],
                                   T11[b * 256 + c] - p1v,
                                   __ATOMIC_RELAXED, __HIP_MEMORY_SCOPE_AGENT);
                __hip_atomic_store(&wv_g[(2 * 6 + b) * 2048 + w],
                                   T14[b * 256 + c] - p1v,
                                   __ATOMIC_RELAXED, __HIP_MEMORY_SCOPE_AGENT);
            }
        }
        __syncthreads();
        if (tid < 8)
            __hip_atomic_store(&cnt[tid], scnt[tid],
                               __ATOMIC_RELAXED, __HIP_MEMORY_SCOPE_AGENT);
        __syncthreads();                       // data stores drained
        if (tid == 0)
            __hip_atomic_store(&flags[1], 1,
                               __ATOMIC_RELAXED, __HIP_MEMORY_SCOPE_AGENT);
        return;
    }

    // ---- chain consumer: one block per (h,b) ----
    const int cid = blk - 96;                  // 0..71
    const int h = cid / 6, b = cid - (cid / 6) * 6;
    const int dg = tid >> 6, eg = tid & 63;

    float* v             = (float*)smem;                       // [256]
    float (*pv)[256]     = (float(*)[256])(smem + 1024);       // [16][256]
    float (*modl)[256]   = (float(*)[256])(smem + 17408);      // [3][256]
    unsigned short* wde  = (unsigned short*)(smem + 20480);    // [2048]
    float* wv0           = (float*)(smem + 24576);
    float* wv1           = (float*)(smem + 32768);
    float* wv2           = (float*)(smem + 40960);
    int*   nw_s          = (int*)(smem + 49152);

    // overlap with producers: v0 + modulation
    if (tid < 256) v[tid] = P2[(h * 6 + b) * 256 + tid];
    if (tid < 768) {
        int s = tid >> 8, ee = tid & 255;
        float fr = (s == 0) ? f1[0]  : (s == 1) ? f2[0]  : f3[0];
        float ph = (s == 0) ? ph1[0] : (s == 1) ? ph2[0] : ph3[0];
        float sn = __sinf((float)ee * TWO_PI * fr + ph);
        float mm = sn * sn * 0.1f + 0.95f;
        modl[s][ee] = (s == 1) ? mm : 1.0f / mm;   // s0: /m, s1: *m, s2: /m
    }
    __syncthreads();

    // one-shot wait for Ch
    if (tid == 0) {
        while (__hip_atomic_load(&flags[0], __ATOMIC_RELAXED,
                                 __HIP_MEMORY_SCOPE_AGENT) < 96)
            __builtin_amdgcn_s_sleep(1);
    }
    __syncthreads();

    // ingest 128 KB fp16 via LLC (bypass possibly-stale L1/L2)
    const unsigned long long* Cq =
        (const unsigned long long*)Ch + (((b << 8) + (dg << 4)) << 6) + eg;
    unsigned long long mraw[16];               // row (dg*16+i), e = eg*4..+3
    #pragma unroll
    for (int i = 0; i < 16; ++i)
        mraw[i] = __hip_atomic_load(Cq + (i << 6), __ATOMIC_RELAXED,
                                    __HIP_MEMORY_SCOPE_AGENT);

    // winner lists (hash finished long ago)
    if (tid == 0) {
        while (__hip_atomic_load(&flags[1], __ATOMIC_RELAXED,
                                 __HIP_MEMORY_SCOPE_AGENT) == 0)
            __builtin_amdgcn_s_sleep(1);
        *nw_s = __hip_atomic_load(&cnt[b], __ATOMIC_RELAXED,
                                  __HIP_MEMORY_SCOPE_AGENT);
    }
    __syncthreads();
    const int nwl = *nw_s;
    for (int i = tid; i < nwl; i += 1024) {
        wde[i] = (unsigned short)__hip_atomic_load(
            &wde_g[b * 2048 + i], __ATOMIC_RELAXED, __HIP_MEMORY_SCOPE_AGENT);
        wv0[i] = __hip_atomic_load(&wv_g[(0 * 6 + b) * 2048 + i],
                                   __ATOMIC_RELAXED, __HIP_MEMORY_SCOPE_AGENT);
        wv1[i] = __hip_atomic_load(&wv_g[(1 * 6 + b) * 2048 + i],
                                   __ATOMIC_RELAXED, __HIP_MEMORY_SCOPE_AGENT);
        wv2[i] = __hip_atomic_load(&wv_g[(2 * 6 + b) * 2048 + i],
                                   __ATOMIC_RELAXED, __HIP_MEMORY_SCOPE_AGENT);
    }
    __syncthreads();

    // ---- three chained stages (r11-proven skeleton, fp16 unpack fused) ----
    const int e256 = tid & 255;
    for (int s = 0; s < 3; ++s) {
        float4 acc = make_float4(0.f, 0.f, 0.f, 0.f);
        #pragma unroll
        for (int j = 0; j < 4; ++j) {
            float4 vv = *(const float4*)&v[(dg << 4) + (j << 2)];
            #pragma unroll
            for (int i = 0; i < 4; ++i) {
                union { unsigned long long u; __half2 h2[2]; } cv;
                cv.u = mraw[(j << 2) + i];
                float2 f01 = __half22float2(cv.h2[0]);
                float2 f23 = __half22float2(cv.h2[1]);
                float vd = (i == 0) ? vv.x : (i == 1) ? vv.y
                         : (i == 2) ? vv.z : vv.w;
                acc.x = fmaf(vd, f01.x, acc.x);
                acc.y = fmaf(vd, f01.y, acc.y);
                acc.z = fmaf(vd, f23.x, acc.z);
                acc.w = fmaf(vd, f23.y, acc.w);
            }
        }
        *(float4*)&pv[dg][eg << 2] = acc;
        __syncthreads();
        {   // reduce 16 -> 4 rows
            int r = tid >> 8;
            float x = pv[r][e256] + pv[r + 4][e256] +
                      pv[r + 8][e256] + pv[r + 12][e256];
            __syncthreads();
            pv[r][e256] = x;
        }
        __syncthreads();
        if (tid < 256)
            pv[0][tid] = (pv[0][tid] + pv[1][tid]) + (pv[2][tid] + pv[3][tid]);
        __syncthreads();
        const float* wvs = (s == 0) ? wv0 : (s == 1) ? wv1 : wv2;
        for (int i = tid; i < nwl; i += 1024) {
            unsigned de = wde[i];
            atomicAdd(&pv[0][de & 255u], v[de >> 8] * wvs[i]);
        }
        __syncthreads();
        if (tid < 256)
            v[tid] = pv[0][tid] * modl[s][tid];
        __syncthreads();
    }
    if (tid < 256) out[(h * 6 + b) * 256 + tid] = v[tid];
}

extern "C" void kernel_launch(void* const* d_in, const int* in_sizes, int n_in,
                              void* d_out, int out_size, void* d_ws, size_t ws_size,
                              hipStream_t stream)
{
    (void)n_in; (void)out_size; (void)ws_size;
    const float* P1  = (const float*)d_in[0];
    const float* P2  = (const float*)d_in[1];
    const float* P3  = (const float*)d_in[2];
    const float* T4  = (const float*)d_in[3];
    const int*   p5  = (const int*)d_in[4];
    const int*   p6  = (const int*)d_in[5];
    const int*   p7  = (const int*)d_in[6];
    const int*   p8  = (const int*)d_in[7];
    const float* f1  = (const float*)d_in[8];
    const float* ph1 = (const float*)d_in[9];
    const float* T11 = (const float*)d_in[10];
    const float* f2  = (const float*)d_in[11];
    const float* ph2 = (const float*)d_in[12];
    const float* T14 = (const float*)d_in[13];
    const float* f3  = (const float*)d_in[14];
    const float* ph3 = (const float*)d_in[15];
    float* out = (float*)d_out;
    int K = in_sizes[4];

    char* ws = (char*)d_ws;
    __half* Ch   = (__half*)(ws);
    int*   cnt   = (int*)  (ws + 786432);
    int*   wde_g = (int*)  (ws + 786496);
    float* wv_g  = (float*)(ws + 835648);
    int*   flags = (int*)  (ws + 983104);

    // zero the flags every call (captured as a memset node)
    hipMemsetAsync(flags, 0, 64, stream);
    hipLaunchKernelGGL(mega_kernel, dim3(169), dim3(1024), 0, stream,
                       P1, P2, P3, T4, p5, p6, p7, p8,
                       f1, ph1, T11, f2, ph2, T14, f3, ph3,
                       Ch, cnt, wde_g, wv_g, flags, out, K);
}

// Round 16
// 23.545 us; speedup vs baseline: 1.3330x; 1.3330x over previous
//
#include <hip/hip_runtime.h>
#include <hip/hip_fp16.h>

#define TWO_PI 6.2831853071795864769f

// ws layout (bytes):
//   Ch   half[393216]     @ 0        (786432)  C = P1 + 0.975*P3 in fp16
//   cnt  int[16]          @ 786432
//   wde  int[6][2048]     @ 786496   (49152)   winner (d<<8)|e per b
//   wv   f32[3][6][2048]  @ 835648   (147456)  per-stage corrections val-P1
//
// Empirical law (r3-r15): per-CU ingest time ~ f(bytes, 16B-requests);
// single dispatch mandatory (gap ~5us), cross-block sync forbidden (+10-25).
// r16 = r14's 2-dispatch fp16 staging, but chain ingests via 8x16-B
// ulonglong2 loads per thread (vs r14's 32x4-B half2) -> 1/4 the requests
// AND 1/4 the bytes of r11's fp32 path.

// Kernel 1 (r14-verbatim): blocks 0..95 build Ch (fp16); block 96 resolves
// last-write-wins winners for ALL b via one 32-bit LDS hash (r6-proven).
__global__ __launch_bounds__(1024) void prep_kernel(
    const float* __restrict__ P1, const float* __restrict__ P3,
    const int* __restrict__ p5, const int* __restrict__ p6,
    const int* __restrict__ p7, const int* __restrict__ p8,
    const float* __restrict__ T4, const float* __restrict__ T11,
    const float* __restrict__ T14,
    __half* __restrict__ Ch, int* __restrict__ cnt,
    int* __restrict__ wde_g, float* __restrict__ wv_g, int K)
{
    const int tid = (int)threadIdx.x;
    const int blk = (int)blockIdx.x;
    if (blk < 96) {                       // 96*1024 float4 = 393216 floats
        int i = blk * 1024 + tid;
        float4 a = ((const float4*)P1)[i];
        float4 c = ((const float4*)P3)[i];
        __half2 h0 = __floats2half2_rn(fmaf(c.x, 0.975f, a.x),
                                       fmaf(c.y, 0.975f, a.y));
        __half2 h1 = __floats2half2_rn(fmaf(c.z, 0.975f, a.z),
                                       fmaf(c.w, 0.975f, a.w));
        __half2* dst = (__half2*)Ch + (i << 1);
        dst[0] = h0;
        dst[1] = h1;
        return;
    }

    __shared__ unsigned pk[2048];         // (b<<24)|(c<<16)|(d<<8)|e
    __shared__ unsigned hmap[4096];
    __shared__ int scnt[8];
    for (int k = tid; k < K; k += 1024)
        pk[k] = ((unsigned)p5[k] << 24) | ((unsigned)p6[k] << 16) |
                ((unsigned)p7[k] << 8) | (unsigned)p8[k];
    for (int i = tid; i < 4096; i += 1024) hmap[i] = 0xFFFFFFFFu;
    if (tid < 8) scnt[tid] = 0;
    __syncthreads();

    for (int k = tid; k < K; k += 1024) {
        unsigned v = pk[k];
        unsigned key  = v & 0xFFFFu;                    // (d<<8)|e
        unsigned full = (key << 3) | (v >> 24);         // 19 bits: (d,e,b)
        unsigned mine = (full << 12) | (unsigned)k;     // k < 4096
        unsigned hh = (full * 2654435761u) >> 20;       // [0,4096)
        for (;;) {
            unsigned prev = atomicCAS(&hmap[hh], 0xFFFFFFFFu, mine);
            if (prev == 0xFFFFFFFFu) break;
            if ((prev >> 12) == full) { atomicMax(&hmap[hh], mine); break; }
            hh = (hh + 1) & 4095u;
        }
    }
    __syncthreads();

    for (int k = tid; k < K; k += 1024) {
        unsigned v = pk[k];
        unsigned key  = v & 0xFFFFu;
        unsigned full = (key << 3) | (v >> 24);
        unsigned hh = (full * 2654435761u) >> 20;
        unsigned cur;
        for (;;) {
            cur = hmap[hh];
            if ((cur >> 12) == full) break;
            hh = (hh + 1) & 4095u;
        }
        if ((cur & 0xFFFu) == (unsigned)k) {          // last write wins
            int b = (int)(v >> 24), c = (int)((v >> 16) & 0xFFu);
            float p1v = P1[(b << 16) | key];          // exact fp32
            int w = atomicAdd(&scnt[b], 1);
            wde_g[b * 2048 + w] = (int)key;
            wv_g[(0 * 6 + b) * 2048 + w] = T4 [b * 256 + c] - p1v;
            wv_g[(1 * 6 + b) * 2048 + w] = T11[b * 256 + c] - p1v;
            wv_g[(2 * 6 + b) * 2048 + w] = T14[b * 256 + c] - p1v;
        }
    }
    __syncthreads();
    if (tid < 8) cnt[tid] = scnt[tid];
}

// Kernel 2: 96 blocks (blk = h*8 + b XCD-swizzled; b>=6 exit) x 1024.
// thread = (dg 0..31, eg 0..31): owns rows dg*8+i (i 0..7), halves
// e = eg*8..+7. m-ingest = 8 x ulonglong2 (16B) pure-load phase -> full MLP.
// fp16 unpack fused into stage FMAs. Winner lists from ws (cached loads,
// dispatch-boundary coherence). 3-stage skeleton r11-proven.
__global__ __launch_bounds__(1024, 4) void chain_kernel(
    const __half* __restrict__ Ch, const float* __restrict__ P2,
    const int* __restrict__ cnt, const int* __restrict__ wde_g,
    const float* __restrict__ wv_g,
    const float* __restrict__ f1, const float* __restrict__ ph1,
    const float* __restrict__ f2, const float* __restrict__ ph2,
    const float* __restrict__ f3, const float* __restrict__ ph3,
    float* __restrict__ out)
{
    const int blk = (int)blockIdx.x;
    const int b = blk & 7;               // = blk % 8 = XCD id
    if (b >= 6) return;
    const int h = blk >> 3;              // 0..11

    __shared__ float v[256];
    __shared__ float pv[32][256];          // 32 KB partials
    __shared__ float modl[3][256];
    __shared__ unsigned short wde[2048];   // winner (d<<8)|e
    __shared__ float wv0[2048], wv1[2048], wv2[2048];

    const int tid = (int)threadIdx.x;
    const int dg = tid >> 5;               // 0..31: rows dg*8 .. dg*8+7
    const int eg = tid & 31;               // halves e = eg*8 .. eg*8+7

    // ---- phase 1: pure-load m-ingest (8 x 16B, no dependent math) ----
    const ulonglong2* Cq = (const ulonglong2*)Ch + (b << 13) + (dg << 8) + eg;
    ulonglong2 mraw[8];                    // row dg*8+i, 8 halves each
    #pragma unroll
    for (int i = 0; i < 8; ++i) mraw[i] = Cq[i << 5];

    // ---- small init (issues while m-loads are in flight) ----
    if (tid < 256) v[tid] = P2[(h * 6 + b) * 256 + tid];
    if (tid < 768) {
        int s = tid >> 8, ee = tid & 255;
        float fr = (s == 0) ? f1[0]  : (s == 1) ? f2[0]  : f3[0];
        float ph = (s == 0) ? ph1[0] : (s == 1) ? ph2[0] : ph3[0];
        float sn = __sinf((float)ee * TWO_PI * fr + ph);
        float mm = sn * sn * 0.1f + 0.95f;
        modl[s][ee] = (s == 1) ? mm : 1.0f / mm;   // s0: /m, s1: *m, s2: /m
    }
    const int nwl = cnt[b];
    for (int i = tid; i < nwl; i += 1024) {
        wde[i] = (unsigned short)wde_g[b * 2048 + i];
        wv0[i] = wv_g[(0 * 6 + b) * 2048 + i];
        wv1[i] = wv_g[(1 * 6 + b) * 2048 + i];
        wv2[i] = wv_g[(2 * 6 + b) * 2048 + i];
    }
    __syncthreads();

    // ---- three chained stages ----
    for (int s = 0; s < 3; ++s) {
        float4 alo = make_float4(0.f, 0.f, 0.f, 0.f);
        float4 ahi = make_float4(0.f, 0.f, 0.f, 0.f);
        #pragma unroll
        for (int i = 0; i < 8; ++i) {
            float vv = v[(dg << 3) + i];   // 2-addr/wave LDS bcast (free)
            union { unsigned long long u; __half2 h2[2]; } lo, hi;
            lo.u = mraw[i].x;
            hi.u = mraw[i].y;
            float2 c0 = __half22float2(lo.h2[0]);
            float2 c1 = __half22float2(lo.h2[1]);
            float2 c2 = __half22float2(hi.h2[0]);
            float2 c3 = __half22float2(hi.h2[1]);
            alo.x = fmaf(vv, c0.x, alo.x); alo.y = fmaf(vv, c0.y, alo.y);
            alo.z = fmaf(vv, c1.x, alo.z); alo.w = fmaf(vv, c1.y, alo.w);
            ahi.x = fmaf(vv, c2.x, ahi.x); ahi.y = fmaf(vv, c2.y, ahi.y);
            ahi.z = fmaf(vv, c3.x, ahi.z); ahi.w = fmaf(vv, c3.y, ahi.w);
        }
        *(float4*)&pv[dg][(eg << 3)]     = alo;
        *(float4*)&pv[dg][(eg << 3) + 4] = ahi;
        __syncthreads();
        if (tid < 256) {                   // reduce 32 -> 1 (indep LDS loads)
            float x0 = 0.f, x1 = 0.f, x2 = 0.f, x3 = 0.f;
            #pragma unroll
            for (int g = 0; g < 32; g += 4) {
                x0 += pv[g][tid];     x1 += pv[g + 1][tid];
                x2 += pv[g + 2][tid]; x3 += pv[g + 3][tid];
            }
            pv[0][tid] = (x0 + x1) + (x2 + x3);
        }
        __syncthreads();
        const float* wvs = (s == 0) ? wv0 : (s == 1) ? wv1 : wv2;
        for (int i = tid; i < nwl; i += 1024) {
            unsigned de = wde[i];
            atomicAdd(&pv[0][de & 255u], v[de >> 8] * wvs[i]);
        }
        __syncthreads();
        if (tid < 256)
            v[tid] = pv[0][tid] * modl[s][tid];
        __syncthreads();
    }
    if (tid < 256) out[(h * 6 + b) * 256 + tid] = v[tid];
}

extern "C" void kernel_launch(void* const* d_in, const int* in_sizes, int n_in,
                              void* d_out, int out_size, void* d_ws, size_t ws_size,
                              hipStream_t stream)
{
    (void)n_in; (void)out_size; (void)ws_size;
    const float* P1  = (const float*)d_in[0];
    const float* P2  = (const float*)d_in[1];
    const float* P3  = (const float*)d_in[2];
    const float* T4  = (const float*)d_in[3];
    const int*   p5  = (const int*)d_in[4];
    const int*   p6  = (const int*)d_in[5];
    const int*   p7  = (const int*)d_in[6];
    const int*   p8  = (const int*)d_in[7];
    const float* f1  = (const float*)d_in[8];
    const float* ph1 = (const float*)d_in[9];
    const float* T11 = (const float*)d_in[10];
    const float* f2  = (const float*)d_in[11];
    const float* ph2 = (const float*)d_in[12];
    const float* T14 = (const float*)d_in[13];
    const float* f3  = (const float*)d_in[14];
    const float* ph3 = (const float*)d_in[15];
    float* out = (float*)d_out;
    int K = in_sizes[4];

    char* ws = (char*)d_ws;
    __half* Ch   = (__half*)(ws);
    int*   cnt   = (int*)  (ws + 786432);
    int*   wde_g = (int*)  (ws + 786496);
    float* wv_g  = (float*)(ws + 835648);

    hipLaunchKernelGGL(prep_kernel, dim3(97), dim3(1024), 0, stream,
                       P1, P3, p5, p6, p7, p8, T4, T11, T14,
                       Ch, cnt, wde_g, wv_g, K);
    hipLaunchKernelGGL(chain_kernel, dim3(96), dim3(1024), 0, stream,
                       Ch, P2, cnt, wde_g, wv_g,
                       f1, ph1, f2, ph2, f3, ph3, out);
}

// Round 17
// 21.845 us; speedup vs baseline: 1.4367x; 1.0778x over previous
//
#include <hip/hip_runtime.h>

#define TWO_PI 6.2831853071795864769f

// ONE dispatch, NO barriers, NO ws. Grid = 96 blocks, blk = h*8 + b:
// blk % 8 = b => the 12 h-chains of batch b land on XCD b (L2 share).
//
// r17 change vs r11 (single variable): SLICE-ROTATED fetch order.
// r13's stagger failed because all 1024 threads issue their first loads at
// once -> whole 512KB footprint touched within one MSHR window (~2.5KB/CU)
// -> lockstep HBM-latency-bound at ~10 B/cyc. Correct granularity: M_b is
// 16 slices of 16 rows (32KB); block h loads slices in order
// (j + start_h) & 15 with start_h = h*16/12 (12 distinct leaders). The
// MSHR window walks slices in program order, so co-XCD blocks keep DISTINCT
// slices in flight: unique lines stream at 12x aggregate, followers hit
// warm XCD-L2 at L2-hit MLP. m4[j] holds slice (j+start)&15, row
// sl*16+dg (static reg index); matvec compensates via wave-uniform LDS
// read v[sl*16+dg].
//
// Scatter = sparse corrections (val_s - P1[pos]) at last-write-wins winners,
// resolved per-block by an LDS hash (key=(d,e), payload=k, atomicMax).
__global__ __launch_bounds__(1024, 4) void fused_chain(
    const float* __restrict__ P1, const float* __restrict__ P2,
    const float* __restrict__ P3, const float* __restrict__ T4,
    const int* __restrict__ p5, const int* __restrict__ p6,
    const int* __restrict__ p7, const int* __restrict__ p8,
    const float* __restrict__ f1, const float* __restrict__ ph1,
    const float* __restrict__ T11, const float* __restrict__ f2,
    const float* __restrict__ ph2, const float* __restrict__ T14,
    const float* __restrict__ f3, const float* __restrict__ ph3,
    float* __restrict__ out, int K)
{
    const int blk = (int)blockIdx.x;
    const int b = blk & 7;               // = blk % 8 = XCD id
    if (b >= 6) return;
    const int h = blk >> 3;              // 0..11

    __shared__ float v[256];
    __shared__ float pv[16][256];          // 16 KB partials
    __shared__ float modl[3][256];
    __shared__ unsigned hmap[4096];        // (key<<12)|k ; empty=0xFFFFFFFF
    __shared__ unsigned short wde[2048];   // winner (d<<8)|e
    __shared__ float wv0[2048], wv1[2048], wv2[2048];
    __shared__ int nw;

    const int tid = (int)threadIdx.x;
    const int dg = tid >> 6;               // 0..15 (wave id: 64 lanes = eg)
    const int eg = tid & 63;               // 0..63
    const int start = (h * 16) / 12;       // 12 distinct leader slices

    // ---- phase 1: slice-rotated m-fill. m4[j] = row ((j+start)&15)*16+dg ----
    const float4* P1v = (const float4*)P1;
    const float4* P3v = (const float4*)P3;
    float4 m4[16];
    #pragma unroll
    for (int j = 0; j < 16; ++j) {
        int sl = (j + start) & 15;
        int row = (b << 8) + (sl << 4) + dg;
        float4 a = P1v[row * 64 + eg];
        float4 c = P3v[row * 64 + eg];
        m4[j].x = fmaf(c.x, 0.975f, a.x);
        m4[j].y = fmaf(c.y, 0.975f, a.y);
        m4[j].z = fmaf(c.z, 0.975f, a.z);
        m4[j].w = fmaf(c.w, 0.975f, a.w);
    }

    // ---- small init (overlaps with loads) ----
    if (tid < 256) v[tid] = P2[(h * 6 + b) * 256 + tid];
    if (tid < 768) {
        int s = tid >> 8, ee = tid & 255;
        float fr = (s == 0) ? f1[0]  : (s == 1) ? f2[0]  : f3[0];
        float ph = (s == 0) ? ph1[0] : (s == 1) ? ph2[0] : ph3[0];
        float sn = __sinf((float)ee * TWO_PI * fr + ph);
        float mm = sn * sn * 0.1f + 0.95f;
        modl[s][ee] = (s == 1) ? mm : 1.0f / mm;   // s0: /m, s1: *m, s2: /m
    }
    for (int i = tid; i < 4096; i += 1024) hmap[i] = 0xFFFFFFFFu;
    if (tid == 0) nw = 0;
    __syncthreads();

    // ---- phase 2: direct hash insert, last-write-wins = max k per (d,e) ----
    for (int k = tid; k < K; k += 1024) {
        if (p5[k] != b) continue;
        unsigned key = ((unsigned)p7[k] << 8) | (unsigned)p8[k];   // 16 bits
        unsigned mine = (key << 12) | (unsigned)k;                 // k < 4096
        unsigned hh = (key * 2654435761u) >> 20;                   // [0,4096)
        for (;;) {
            unsigned prev = atomicCAS(&hmap[hh], 0xFFFFFFFFu, mine);
            if (prev == 0xFFFFFFFFu) break;
            if ((prev >> 12) == key) { atomicMax(&hmap[hh], mine); break; }
            hh = (hh + 1) & 4095u;
        }
    }
    __syncthreads();

    // ---- phase 3: winner readback -> sparse corrections ----
    for (int k = tid; k < K; k += 1024) {
        if (p5[k] != b) continue;
        unsigned key = ((unsigned)p7[k] << 8) | (unsigned)p8[k];
        unsigned hh = (key * 2654435761u) >> 20;
        unsigned cur;
        for (;;) {
            cur = hmap[hh];
            if ((cur >> 12) == key) break;
            hh = (hh + 1) & 4095u;
        }
        if ((cur & 0xFFFu) == (unsigned)k) {        // winner (last write)
            int c = p6[k];
            float p1v = P1[(b << 16) | key];        // b*65536 + d*256 + e
            int w = atomicAdd(&nw, 1);
            wde[w] = (unsigned short)key;
            wv0[w] = T4 [b * 256 + c] - p1v;
            wv1[w] = T11[b * 256 + c] - p1v;
            wv2[w] = T14[b * 256 + c] - p1v;
        }
    }
    __syncthreads();
    const int nwl = nw;

    // ---- phase 4: three chained stages ----
    const int e256 = tid & 255;
    for (int s = 0; s < 3; ++s) {
        float4 acc = make_float4(0.f, 0.f, 0.f, 0.f);
        #pragma unroll
        for (int j = 0; j < 16; ++j) {
            // wave-uniform LDS broadcast; row of m4[j] is ((j+start)&15)*16+dg
            float vv = v[(((j + start) & 15) << 4) + dg];
            acc.x = fmaf(vv, m4[j].x, acc.x);
            acc.y = fmaf(vv, m4[j].y, acc.y);
            acc.z = fmaf(vv, m4[j].z, acc.z);
            acc.w = fmaf(vv, m4[j].w, acc.w);
        }
        *(float4*)&pv[dg][eg << 2] = acc;
        __syncthreads();
        {   // reduce 16 -> 4 rows
            int r = tid >> 8;                       // 0..3
            float x = pv[r][e256] + pv[r + 4][e256] +
                      pv[r + 8][e256] + pv[r + 12][e256];
            __syncthreads();
            pv[r][e256] = x;
        }
        __syncthreads();
        if (tid < 256)                              // reduce 4 -> 1
            pv[0][tid] = (pv[0][tid] + pv[1][tid]) + (pv[2][tid] + pv[3][tid]);
        __syncthreads();
        const float* wvs = (s == 0) ? wv0 : (s == 1) ? wv1 : wv2;
        for (int i = tid; i < nwl; i += 1024) {
            unsigned de = wde[i];
            atomicAdd(&pv[0][de & 255u], v[de >> 8] * wvs[i]);
        }
        __syncthreads();
        if (tid < 256)
            v[tid] = pv[0][tid] * modl[s][tid];
        __syncthreads();
    }
    if (tid < 256) out[(h * 6 + b) * 256 + tid] = v[tid];
}

extern "C" void kernel_launch(void* const* d_in, const int* in_sizes, int n_in,
                              void* d_out, int out_size, void* d_ws, size_t ws_size,
                              hipStream_t stream)
{
    (void)n_in; (void)out_size; (void)d_ws; (void)ws_size;
    const float* P1  = (const float*)d_in[0];
    const float* P2  = (const float*)d_in[1];
    const float* P3  = (const float*)d_in[2];
    const float* T4  = (const float*)d_in[3];
    const int*   p5  = (const int*)d_in[4];
    const int*   p6  = (const int*)d_in[5];
    const int*   p7  = (const int*)d_in[6];
    const int*   p8  = (const int*)d_in[7];
    const float* f1  = (const float*)d_in[8];
    const float* ph1 = (const float*)d_in[9];
    const float* T11 = (const float*)d_in[10];
    const float* f2  = (const float*)d_in[11];
    const float* ph2 = (const float*)d_in[12];
    const float* T14 = (const float*)d_in[13];
    const float* f3  = (const float*)d_in[14];
    const float* ph3 = (const float*)d_in[15];
    float* out = (float*)d_out;
    int K = in_sizes[4];

    hipLaunchKernelGGL(fused_chain, dim3(96), dim3(1024), 0, stream,
                       P1, P2, P3, T4, p5, p6, p7, p8,
                       f1, ph1, T11, f2, ph2, T14, f3, ph3, out, K);
}

// Round 18
// 20.190 us; speedup vs baseline: 1.5544x; 1.0819x over previous
//
#include <hip/hip_runtime.h>

#define TWO_PI 6.2831853071795864769f

typedef float f4v __attribute__((ext_vector_type(4)));

// ONE dispatch, NO barriers, NO ws. Grid = 96 blocks, blk = h*8 + b:
// blk % 8 = b => the 12 h-chains of batch b land on XCD b (L2 share).
//
// r18 change vs r11 (single variable): NONTEMPORAL m-fill loads.
// Model (fits r3-r17): per-CU ingest wall ~10 B/cyc == L1 MSHR capacity
// (~64 lines x 128B / ~800cyc). Order/source-insensitive: stagger (r13),
// slice rotation (r17), L2 warmth (r11 swizzle) all neutral. nt loads skip
// L1 allocation -> tracked by per-wave vmcnt (64 ops/wave x 16 waves), not
// the CU MSHR pool -> ceiling moves to per-CU L2 request rate (~56 B/cyc).
//
// Scatter = sparse corrections (val_s - P1[pos]) at last-write-wins winners,
// resolved per-block by an LDS hash (key=(d,e), payload=k, atomicMax).
__global__ __launch_bounds__(1024, 4) void fused_chain(
    const float* __restrict__ P1, const float* __restrict__ P2,
    const float* __restrict__ P3, const float* __restrict__ T4,
    const int* __restrict__ p5, const int* __restrict__ p6,
    const int* __restrict__ p7, const int* __restrict__ p8,
    const float* __restrict__ f1, const float* __restrict__ ph1,
    const float* __restrict__ T11, const float* __restrict__ f2,
    const float* __restrict__ ph2, const float* __restrict__ T14,
    const float* __restrict__ f3, const float* __restrict__ ph3,
    float* __restrict__ out, int K)
{
    const int blk = (int)blockIdx.x;
    const int b = blk & 7;               // = blk % 8 = XCD id
    if (b >= 6) return;
    const int h = blk >> 3;              // 0..11

    __shared__ float v[256];
    __shared__ float pv[16][256];          // 16 KB partials
    __shared__ float modl[3][256];
    __shared__ unsigned hmap[4096];        // (key<<12)|k ; empty=0xFFFFFFFF
    __shared__ unsigned short wde[2048];   // winner (d<<8)|e
    __shared__ float wv0[2048], wv1[2048], wv2[2048];
    __shared__ int nw;

    const int tid = (int)threadIdx.x;
    const int dg = tid >> 6;               // 0..15
    const int eg = tid & 63;               // 0..63

    // ---- phase 1: m-fill via NONTEMPORAL loads (L1-bypass, vmcnt-tracked) ----
    const f4v* P1v = (const f4v*)P1;
    const f4v* P3v = (const f4v*)P3;
    const int rbase = (b << 8) + (dg << 4);
    float4 m4[16];
    #pragma unroll
    for (int i = 0; i < 16; ++i) {
        f4v a = __builtin_nontemporal_load(&P1v[(rbase + i) * 64 + eg]);
        f4v c = __builtin_nontemporal_load(&P3v[(rbase + i) * 64 + eg]);
        m4[i].x = fmaf(c.x, 0.975f, a.x);
        m4[i].y = fmaf(c.y, 0.975f, a.y);
        m4[i].z = fmaf(c.z, 0.975f, a.z);
        m4[i].w = fmaf(c.w, 0.975f, a.w);
    }

    // ---- small init (overlaps with loads) ----
    if (tid < 256) v[tid] = P2[(h * 6 + b) * 256 + tid];
    if (tid < 768) {
        int s = tid >> 8, ee = tid & 255;
        float fr = (s == 0) ? f1[0]  : (s == 1) ? f2[0]  : f3[0];
        float ph = (s == 0) ? ph1[0] : (s == 1) ? ph2[0] : ph3[0];
        float sn = __sinf((float)ee * TWO_PI * fr + ph);
        float mm = sn * sn * 0.1f + 0.95f;
        modl[s][ee] = (s == 1) ? mm : 1.0f / mm;   // s0: /m, s1: *m, s2: /m
    }
    for (int i = tid; i < 4096; i += 1024) hmap[i] = 0xFFFFFFFFu;
    if (tid == 0) nw = 0;
    __syncthreads();

    // ---- phase 2: direct hash insert, last-write-wins = max k per (d,e) ----
    for (int k = tid; k < K; k += 1024) {
        if (p5[k] != b) continue;
        unsigned key = ((unsigned)p7[k] << 8) | (unsigned)p8[k];   // 16 bits
        unsigned mine = (key << 12) | (unsigned)k;                 // k < 4096
        unsigned hh = (key * 2654435761u) >> 20;                   // [0,4096)
        for (;;) {
            unsigned prev = atomicCAS(&hmap[hh], 0xFFFFFFFFu, mine);
            if (prev == 0xFFFFFFFFu) break;
            if ((prev >> 12) == key) { atomicMax(&hmap[hh], mine); break; }
            hh = (hh + 1) & 4095u;
        }
    }
    __syncthreads();

    // ---- phase 3: winner readback -> sparse corrections ----
    for (int k = tid; k < K; k += 1024) {
        if (p5[k] != b) continue;
        unsigned key = ((unsigned)p7[k] << 8) | (unsigned)p8[k];
        unsigned hh = (key * 2654435761u) >> 20;
        unsigned cur;
        for (;;) {
            cur = hmap[hh];
            if ((cur >> 12) == key) break;
            hh = (hh + 1) & 4095u;
        }
        if ((cur & 0xFFFu) == (unsigned)k) {        // winner (last write)
            int c = p6[k];
            float p1v = P1[(b << 16) | key];        // b*65536 + d*256 + e
            int w = atomicAdd(&nw, 1);
            wde[w] = (unsigned short)key;
            wv0[w] = T4 [b * 256 + c] - p1v;
            wv1[w] = T11[b * 256 + c] - p1v;
            wv2[w] = T14[b * 256 + c] - p1v;
        }
    }
    __syncthreads();
    const int nwl = nw;

    // ---- phase 4: three chained stages ----
    const int e256 = tid & 255;
    for (int s = 0; s < 3; ++s) {
        float4 acc = make_float4(0.f, 0.f, 0.f, 0.f);
        #pragma unroll
        for (int j = 0; j < 4; ++j) {
            float4 vv = *(const float4*)&v[(dg << 4) + (j << 2)];
            float4 m0 = m4[(j << 2) + 0];
            float4 m1 = m4[(j << 2) + 1];
            float4 m2 = m4[(j << 2) + 2];
            float4 m3 = m4[(j << 2) + 3];
            acc.x = fmaf(vv.x, m0.x, acc.x); acc.y = fmaf(vv.x, m0.y, acc.y);
            acc.z = fmaf(vv.x, m0.z, acc.z); acc.w = fmaf(vv.x, m0.w, acc.w);
            acc.x = fmaf(vv.y, m1.x, acc.x); acc.y = fmaf(vv.y, m1.y, acc.y);
            acc.z = fmaf(vv.y, m1.z, acc.z); acc.w = fmaf(vv.y, m1.w, acc.w);
            acc.x = fmaf(vv.z, m2.x, acc.x); acc.y = fmaf(vv.z, m2.y, acc.y);
            acc.z = fmaf(vv.z, m2.z, acc.z); acc.w = fmaf(vv.z, m2.w, acc.w);
            acc.x = fmaf(vv.w, m3.x, acc.x); acc.y = fmaf(vv.w, m3.y, acc.y);
            acc.z = fmaf(vv.w, m3.z, acc.z); acc.w = fmaf(vv.w, m3.w, acc.w);
        }
        *(float4*)&pv[dg][eg << 2] = acc;
        __syncthreads();
        {   // reduce 16 -> 4 rows
            int r = tid >> 8;                       // 0..3
            float x = pv[r][e256] + pv[r + 4][e256] +
                      pv[r + 8][e256] + pv[r + 12][e256];
            __syncthreads();
            pv[r][e256] = x;
        }
        __syncthreads();
        if (tid < 256)                              // reduce 4 -> 1
            pv[0][tid] = (pv[0][tid] + pv[1][tid]) + (pv[2][tid] + pv[3][tid]);
        __syncthreads();
        const float* wvs = (s == 0) ? wv0 : (s == 1) ? wv1 : wv2;
        for (int i = tid; i < nwl; i += 1024) {
            unsigned de = wde[i];
            atomicAdd(&pv[0][de & 255u], v[de >> 8] * wvs[i]);
        }
        __syncthreads();
        if (tid < 256)
            v[tid] = pv[0][tid] * modl[s][tid];
        __syncthreads();
    }
    if (tid < 256) out[(h * 6 + b) * 256 + tid] = v[tid];
}

extern "C" void kernel_launch(void* const* d_in, const int* in_sizes, int n_in,
                              void* d_out, int out_size, void* d_ws, size_t ws_size,
                              hipStream_t stream)
{
    (void)n_in; (void)out_size; (void)d_ws; (void)ws_size;
    const float* P1  = (const float*)d_in[0];
    const float* P2  = (const float*)d_in[1];
    const float* P3  = (const float*)d_in[2];
    const float* T4  = (const float*)d_in[3];
    const int*   p5  = (const int*)d_in[4];
    const int*   p6  = (const int*)d_in[5];
    const int*   p7  = (const int*)d_in[6];
    const int*   p8  = (const int*)d_in[7];
    const float* f1  = (const float*)d_in[8];
    const float* ph1 = (const float*)d_in[9];
    const float* T11 = (const float*)d_in[10];
    const float* f2  = (const float*)d_in[11];
    const float* ph2 = (const float*)d_in[12];
    const float* T14 = (const float*)d_in[13];
    const float* f3  = (const float*)d_in[14];
    const float* ph3 = (const float*)d_in[15];
    float* out = (float*)d_out;
    int K = in_sizes[4];

    hipLaunchKernelGGL(fused_chain, dim3(96), dim3(1024), 0, stream,
                       P1, P2, P3, T4, p5, p6, p7, p8,
                       f1, ph1, T11, f2, ph2, T14, f3, ph3, out, K);
}